// Round 4
// baseline (1144.440 us; speedup 1.0000x reference)
//
#include <hip/hip_runtime.h>
#include <math.h>

typedef __bf16 bf16x8 __attribute__((ext_vector_type(8)));
typedef __bf16 bf16x4 __attribute__((ext_vector_type(4)));
typedef float f32x4 __attribute__((ext_vector_type(4)));

#define NTOK 147456
#define LTOK 9216
#define ALPHA 1.8612097182041991f
#define QSCALE 5.656854249492380196f
#define MFMA16(a,b,c) __builtin_amdgcn_mfma_f32_16x16x32_bf16((a),(b),(c),0,0,0)
#define SWB(row,kb) ((kb) ^ ((row)&7))

__device__ __forceinline__ float gelu_tanh(float x) {
    // tanh-form GELU; |err| vs exact erf-GELU < ~1e-3, NaN-safe at +-inf
    const float u = 0.7978845608028654f * (x + 0.044715f * x * x * x);
    const float e = __expf(2.0f * u);
    const float th = 1.0f - 2.0f / (e + 1.0f);
    return 0.5f * x * (1.0f + th);
}

// ---------------------------------------------------------------------------
// k0: weights -> bf16 transposed [out][k]
// ---------------------------------------------------------------------------
__global__ __launch_bounds__(256) void k0_prep(
    const float* __restrict__ qkv_w, const float* __restrict__ proj_w,
    const float* __restrict__ fc1_w, const float* __restrict__ fc2_w,
    __bf16* __restrict__ qkvT, __bf16* __restrict__ projT,
    __bf16* __restrict__ w1T, __bf16* __restrict__ w2T)
{
    const int id = blockIdx.x * 256 + threadIdx.x;
    if (id < 196608) {
        const int o = id >> 8, k = id & 255;
        qkvT[id] = (__bf16)qkv_w[k * 768 + o];
    } else if (id < 262144) {
        const int i = id - 196608, o = i >> 8, k = i & 255;
        projT[i] = (__bf16)proj_w[k * 256 + o];
    } else if (id < 524288) {
        const int i = id - 262144, o = i >> 8, k = i & 255;
        w1T[i] = (__bf16)fc1_w[k * 1024 + o];
    } else {
        const int i = id - 524288, o = i >> 10, k = i & 1023;
        w2T[i] = (__bf16)fc2_w[k * 256 + o];
    }
}

// ---------------------------------------------------------------------------
// k1a: QKV GEMM with fused shift+window gather. grid (1152,3), block 512.
// ---------------------------------------------------------------------------
__global__ __launch_bounds__(512) void k1a_qkv(
    const float* __restrict__ x, const __bf16* __restrict__ qkvT,
    const float* __restrict__ qkv_b, __bf16* __restrict__ qkv)
{
    __shared__ __attribute__((aligned(16))) __bf16 As[128][64];
    __shared__ __attribute__((aligned(16))) __bf16 Bs[256][64];
    const int t = threadIdx.x;
    const int wid = t >> 6, lane = t & 63;
    const int l15 = lane & 15, lg = lane >> 4;
    const int mb = blockIdx.x, nb = blockIdx.y;
    const int wm = wid >> 2, wn = wid & 3;

    const f32x4 fzero = {0.f, 0.f, 0.f, 0.f};
    f32x4 acc[4][4];
    #pragma unroll
    for (int i = 0; i < 4; ++i)
        #pragma unroll
        for (int j = 0; j < 4; ++j) acc[i][j] = fzero;

    for (int kc = 0; kc < 4; ++kc) {
        __syncthreads();
        for (int o = t; o < 128 * 8; o += 512) {
            const int row = o >> 3, kb = o & 7;
            const int r = mb * 128 + row;
            const int b = r / LTOK, rem = r % LTOK;
            const int w_ = rem / 36, nn = rem % 36;
            const int gh = ((w_ >> 4) * 6 + nn / 6 + 3) % 96;
            const int gw = ((w_ & 15) * 6 + nn % 6 + 3) % 96;
            const float* src = x + ((size_t)b * LTOK + gh * 96 + gw) * 256 + kc * 64 + kb * 8;
            const float4 f0 = *(const float4*)src;
            const float4 f1 = *(const float4*)(src + 4);
            bf16x8 p;
            p[0] = (__bf16)f0.x; p[1] = (__bf16)f0.y; p[2] = (__bf16)f0.z; p[3] = (__bf16)f0.w;
            p[4] = (__bf16)f1.x; p[5] = (__bf16)f1.y; p[6] = (__bf16)f1.z; p[7] = (__bf16)f1.w;
            *(bf16x8*)&As[row][SWB(row, kb) * 8] = p;
        }
        for (int o = t; o < 256 * 8; o += 512) {
            const int row = o >> 3, kb = o & 7;
            *(uint4*)&Bs[row][SWB(row, kb) * 8] =
                *(const uint4*)(qkvT + (size_t)(nb * 256 + row) * 256 + kc * 64 + kb * 8);
        }
        __syncthreads();
        #pragma unroll
        for (int kk = 0; kk < 2; ++kk) {
            bf16x8 af[4], bfr[4];
            #pragma unroll
            for (int rt = 0; rt < 4; ++rt) {
                const int ar = wm * 64 + rt * 16 + l15;
                af[rt] = *(const bf16x8*)&As[ar][((kk * 4 + lg) ^ (ar & 7)) * 8];
            }
            #pragma unroll
            for (int ct = 0; ct < 4; ++ct) {
                const int br = wn * 64 + ct * 16 + l15;
                bfr[ct] = *(const bf16x8*)&Bs[br][((kk * 4 + lg) ^ (br & 7)) * 8];
            }
            #pragma unroll
            for (int rt = 0; rt < 4; ++rt)
                #pragma unroll
                for (int ct = 0; ct < 4; ++ct)
                    acc[rt][ct] = MFMA16(af[rt], bfr[ct], acc[rt][ct]);
        }
    }

    const float scale = (nb == 0) ? QSCALE : 1.0f;
    #pragma unroll
    for (int ct = 0; ct < 4; ++ct) {
        const int col = nb * 256 + wn * 64 + ct * 16 + l15;
        const float bias = qkv_b[col];
        #pragma unroll
        for (int rt = 0; rt < 4; ++rt) {
            #pragma unroll
            for (int q = 0; q < 4; ++q) {
                const int r = mb * 128 + wm * 64 + rt * 16 + lg * 4 + q;
                qkv[(size_t)r * 768 + col] = (__bf16)((acc[rt][ct][q] + bias) * scale);
            }
        }
    }
}

// ---------------------------------------------------------------------------
// k1b: per-window MFMA attention. grid 4096, block 256 (4 waves).
// ---------------------------------------------------------------------------
__global__ __launch_bounds__(256) void k1b_attn(
    const __bf16* __restrict__ qkv, const float* __restrict__ bias_table,
    __bf16* __restrict__ attnout)
{
    __shared__ float bias_s[121][8];
    __shared__ __attribute__((aligned(16))) __bf16 P[4][48][64];
    __shared__ __attribute__((aligned(16))) __bf16 vT[4][32][64];

    const int blk = blockIdx.x;
    const int win = blk & 255;
    const int wh = win >> 4, ww = win & 15;
    const int t = threadIdx.x;
    const int wv = t >> 6, lane = t & 63;
    const int l15 = lane & 15, lg = lane >> 4;
    const size_t rowbase = (size_t)blk * 36;

    for (int o = t; o < 968; o += 256) ((float*)bias_s)[o] = bias_table[o];
    const uint4 z4 = {0u, 0u, 0u, 0u};
    for (int o = t; o < 1536; o += 256) ((uint4*)P)[o] = z4;
    for (int o = t; o < 1024; o += 256) ((uint4*)vT)[o] = z4;
    __syncthreads();

    const f32x4 fzero = {0.f, 0.f, 0.f, 0.f};
    int i2_[3], j2_[3], g2_[3];
    #pragma unroll
    for (int ct = 0; ct < 3; ++ct) {
        const int m = ct * 16 + l15;
        const int mm = m < 36 ? m : 35;
        i2_[ct] = mm / 6; j2_[ct] = mm - i2_[ct] * 6;
        const int hg = (wh < 15) ? 0 : (i2_[ct] < 3 ? 1 : 2);
        const int wg = (ww < 15) ? 0 : (j2_[ct] < 3 ? 1 : 2);
        g2_[ct] = hg * 3 + wg;
    }

    for (int hh = 0; hh < 2; ++hh) {
        const int h = hh * 4 + wv;

        bf16x8 aq[3], bk[3];
        #pragma unroll
        for (int rt = 0; rt < 3; ++rt) {
            const int n = rt * 16 + l15;
            const int g = n < 36 ? n : 35;
            const __bf16* p = qkv + (rowbase + g) * 768 + h * 32 + lg * 8;
            aq[rt] = *(const bf16x8*)p;
            bk[rt] = *(const bf16x8*)(p + 256);
            if (n >= 36) {
                bf16x8 z;
                #pragma unroll
                for (int e = 0; e < 8; ++e) z[e] = (__bf16)0.0f;
                bk[rt] = z;
            }
        }

        #pragma unroll
        for (int i = 0; i < 5; ++i) {
            const int idx = i * 64 + lane;
            if (idx < 288) {
                const int m = idx >> 3, d4 = (idx & 7) * 4;
                const bf16x4 vv = *(const bf16x4*)(qkv + (rowbase + m) * 768 + 512 + h * 32 + d4);
                #pragma unroll
                for (int e = 0; e < 4; ++e) {
                    const int d = d4 + e;
                    vT[wv][d][(((m >> 3) ^ (d & 7)) * 8) + (m & 7)] = vv[e];
                }
            }
        }

        f32x4 s[3][3];
        #pragma unroll
        for (int rt = 0; rt < 3; ++rt)
            #pragma unroll
            for (int ct = 0; ct < 3; ++ct)
                s[rt][ct] = MFMA16(aq[rt], bk[ct], fzero);

        float inv_[3][4];
        #pragma unroll
        for (int rt = 0; rt < 3; ++rt) {
            #pragma unroll
            for (int q = 0; q < 4; ++q) {
                const int n0 = rt * 16 + lg * 4 + q;
                const int nn = n0 < 36 ? n0 : 35;
                const int i1 = nn / 6, j1 = nn - i1 * 6;
                const int hg1 = (wh < 15) ? 0 : (i1 < 3 ? 1 : 2);
                const int wg1 = (ww < 15) ? 0 : (j1 < 3 ? 1 : 2);
                const int g1 = hg1 * 3 + wg1;
                #pragma unroll
                for (int ct = 0; ct < 3; ++ct) {
                    const int m = ct * 16 + l15;
                    float val;
                    if (m < 36) {
                        val = s[rt][ct][q] + bias_s[(i1 - i2_[ct] + 5) * 11 + (j1 - j2_[ct] + 5)][h];
                        if (g1 != g2_[ct]) val -= 100.0f;
                    } else {
                        val = -1e30f;
                    }
                    s[rt][ct][q] = val;
                }
                float mx = fmaxf(fmaxf(s[rt][0][q], s[rt][1][q]), s[rt][2][q]);
                mx = fmaxf(mx, __shfl_xor(mx, 1, 16));
                mx = fmaxf(mx, __shfl_xor(mx, 2, 16));
                mx = fmaxf(mx, __shfl_xor(mx, 4, 16));
                mx = fmaxf(mx, __shfl_xor(mx, 8, 16));
                float sum = 0.f;
                #pragma unroll
                for (int ct = 0; ct < 3; ++ct) {
                    const float e = __expf(s[rt][ct][q] - mx);
                    s[rt][ct][q] = e;
                    sum += e;
                }
                sum += __shfl_xor(sum, 1, 16);
                sum += __shfl_xor(sum, 2, 16);
                sum += __shfl_xor(sum, 4, 16);
                sum += __shfl_xor(sum, 8, 16);
                inv_[rt][q] = 1.0f / sum;
            }
        }

        #pragma unroll
        for (int rt = 0; rt < 3; ++rt)
            #pragma unroll
            for (int q = 0; q < 4; ++q) {
                const int row = rt * 16 + lg * 4 + q;
                #pragma unroll
                for (int ct = 0; ct < 3; ++ct) {
                    const int m = ct * 16 + l15;
                    P[wv][row][(((m >> 3) ^ (row & 7)) * 8) + (m & 7)] = (__bf16)s[rt][ct][q];
                }
            }
        __syncthreads();

        f32x4 ov[3][2];
        #pragma unroll
        for (int rt = 0; rt < 3; ++rt)
            #pragma unroll
            for (int cd = 0; cd < 2; ++cd) ov[rt][cd] = fzero;
        #pragma unroll
        for (int kk = 0; kk < 2; ++kk) {
            bf16x8 pa[3], bv[2];
            #pragma unroll
            for (int rt = 0; rt < 3; ++rt) {
                const int ar = rt * 16 + l15;
                pa[rt] = *(const bf16x8*)&P[wv][ar][((kk * 4 + lg) ^ (ar & 7)) * 8];
            }
            #pragma unroll
            for (int cd = 0; cd < 2; ++cd) {
                const int d = cd * 16 + l15;
                bv[cd] = *(const bf16x8*)&vT[wv][d][((kk * 4 + lg) ^ (d & 7)) * 8];
            }
            #pragma unroll
            for (int rt = 0; rt < 3; ++rt)
                #pragma unroll
                for (int cd = 0; cd < 2; ++cd)
                    ov[rt][cd] = MFMA16(pa[rt], bv[cd], ov[rt][cd]);
        }

        #pragma unroll
        for (int rt = 0; rt < 3; ++rt)
            #pragma unroll
            for (int cd = 0; cd < 2; ++cd)
                #pragma unroll
                for (int q = 0; q < 4; ++q) {
                    const int n = rt * 16 + lg * 4 + q;
                    if (n < 36)
                        attnout[(rowbase + n) * 256 + h * 32 + cd * 16 + l15] =
                            (__bf16)(ov[rt][cd][q] * inv_[rt][q]);
                }
        __syncthreads();
    }
}

// ---------------------------------------------------------------------------
// k2: MFMA proj (BM=128, 4x4 wave tiles) + roll permute + residual + LN1 -> x1
// grid 1152, block 512
// ---------------------------------------------------------------------------
__global__ __launch_bounds__(512) void k2_proj_ln(
    const __bf16* __restrict__ attnout, const __bf16* __restrict__ projT,
    const float* __restrict__ proj_b, const float* __restrict__ x,
    const float* __restrict__ n1w, const float* __restrict__ n1b,
    float* __restrict__ x1)
{
    __shared__ __attribute__((aligned(16))) __bf16 As[128][64];
    __shared__ __attribute__((aligned(16))) __bf16 Bs[256][64];
    __shared__ float ps[128][4], ps2[128][4];
    const int t = threadIdx.x;
    const int wid = t >> 6, lane = t & 63;
    const int l15 = lane & 15, lg = lane >> 4;
    const int mb = blockIdx.x;
    const int wm = wid >> 2, wn = wid & 3;

    const f32x4 fzero = {0.f, 0.f, 0.f, 0.f};
    f32x4 acc[4][4];
    #pragma unroll
    for (int i = 0; i < 4; ++i)
        #pragma unroll
        for (int j = 0; j < 4; ++j) acc[i][j] = fzero;

    for (int kc = 0; kc < 4; ++kc) {
        __syncthreads();
        for (int o = t; o < 128 * 8; o += 512) {
            const int row = o >> 3, kb = o & 7;
            *(uint4*)&As[row][SWB(row, kb) * 8] =
                *(const uint4*)(attnout + (size_t)(mb * 128 + row) * 256 + kc * 64 + kb * 8);
        }
        for (int o = t; o < 256 * 8; o += 512) {
            const int row = o >> 3, kb = o & 7;
            *(uint4*)&Bs[row][SWB(row, kb) * 8] =
                *(const uint4*)(projT + (size_t)row * 256 + kc * 64 + kb * 8);
        }
        __syncthreads();
        #pragma unroll
        for (int kk = 0; kk < 2; ++kk) {
            bf16x8 af[4], bfr[4];
            #pragma unroll
            for (int rt = 0; rt < 4; ++rt) {
                const int ar = wm * 64 + rt * 16 + l15;
                af[rt] = *(const bf16x8*)&As[ar][((kk * 4 + lg) ^ (ar & 7)) * 8];
            }
            #pragma unroll
            for (int ct = 0; ct < 4; ++ct) {
                const int br = wn * 64 + ct * 16 + l15;
                bfr[ct] = *(const bf16x8*)&Bs[br][((kk * 4 + lg) ^ (br & 7)) * 8];
            }
            #pragma unroll
            for (int rt = 0; rt < 4; ++rt)
                #pragma unroll
                for (int ct = 0; ct < 4; ++ct)
                    acc[rt][ct] = MFMA16(af[rt], bfr[ct], acc[rt][ct]);
        }
    }

    // epilogue: bias + permuted residual; partial LN sums -> LDS
    int dtok_[4][4];
    #pragma unroll
    for (int rt = 0; rt < 4; ++rt) {
        #pragma unroll
        for (int q = 0; q < 4; ++q) {
            const int rowl = wm * 64 + rt * 16 + lg * 4 + q;
            const int tok = mb * 128 + rowl;
            const int b = tok / LTOK, l = tok % LTOK;
            const int hh = l / 96, wwp = l % 96;
            const int dtok = b * LTOK + ((hh + 3) % 96) * 96 + ((wwp + 3) % 96);
            dtok_[rt][q] = dtok;
            float s = 0.f, s2 = 0.f;
            #pragma unroll
            for (int ct = 0; ct < 4; ++ct) {
                const int col = wn * 64 + ct * 16 + l15;
                const float v = acc[rt][ct][q] + proj_b[col] + ALPHA * x[(size_t)dtok * 256 + col];
                acc[rt][ct][q] = v;
                s += v; s2 += v * v;
            }
            s  += __shfl_xor(s, 1, 16);  s += __shfl_xor(s, 2, 16);
            s  += __shfl_xor(s, 4, 16);  s += __shfl_xor(s, 8, 16);
            s2 += __shfl_xor(s2, 1, 16); s2 += __shfl_xor(s2, 2, 16);
            s2 += __shfl_xor(s2, 4, 16); s2 += __shfl_xor(s2, 8, 16);
            if (l15 == 0) { ps[rowl][wn] = s; ps2[rowl][wn] = s2; }
        }
    }
    __syncthreads();
    #pragma unroll
    for (int rt = 0; rt < 4; ++rt) {
        #pragma unroll
        for (int q = 0; q < 4; ++q) {
            const int rowl = wm * 64 + rt * 16 + lg * 4 + q;
            const float S  = ps[rowl][0] + ps[rowl][1] + ps[rowl][2] + ps[rowl][3];
            const float S2 = ps2[rowl][0] + ps2[rowl][1] + ps2[rowl][2] + ps2[rowl][3];
            const float mu = S * (1.0f / 256.0f);
            const float var = S2 * (1.0f / 256.0f) - mu * mu;
            const float rstd = rsqrtf(var + 1e-5f);
            float* op = x1 + (size_t)dtok_[rt][q] * 256;
            #pragma unroll
            for (int ct = 0; ct < 4; ++ct) {
                const int col = wn * 64 + ct * 16 + l15;
                op[col] = (acc[rt][ct][q] - mu) * rstd * n1w[col] + n1b[col];
            }
        }
    }
}

// ---------------------------------------------------------------------------
// k3a: fc1 + GELU -> hmid bf16 (one token half). grid (576,4), block 512
// ---------------------------------------------------------------------------
__global__ __launch_bounds__(512) void k3a_fc1(
    const float* __restrict__ x1, const __bf16* __restrict__ w1T,
    const float* __restrict__ fc1_b, __bf16* __restrict__ hmid, int row0)
{
    __shared__ __attribute__((aligned(16))) __bf16 As[128][64];
    __shared__ __attribute__((aligned(16))) __bf16 Bs[256][64];
    const int t = threadIdx.x;
    const int wid = t >> 6, lane = t & 63;
    const int l15 = lane & 15, lg = lane >> 4;
    const int mb = blockIdx.x, nb = blockIdx.y;
    const int wm = wid >> 2, wn = wid & 3;

    const f32x4 fzero = {0.f, 0.f, 0.f, 0.f};
    f32x4 acc[4][4];
    #pragma unroll
    for (int i = 0; i < 4; ++i)
        #pragma unroll
        for (int j = 0; j < 4; ++j) acc[i][j] = fzero;

    for (int kc = 0; kc < 4; ++kc) {
        __syncthreads();
        for (int o = t; o < 128 * 8; o += 512) {
            const int row = o >> 3, kb = o & 7;
            const float* src = x1 + (size_t)(row0 + mb * 128 + row) * 256 + kc * 64 + kb * 8;
            const float4 f0 = *(const float4*)src;
            const float4 f1 = *(const float4*)(src + 4);
            bf16x8 p;
            p[0] = (__bf16)f0.x; p[1] = (__bf16)f0.y; p[2] = (__bf16)f0.z; p[3] = (__bf16)f0.w;
            p[4] = (__bf16)f1.x; p[5] = (__bf16)f1.y; p[6] = (__bf16)f1.z; p[7] = (__bf16)f1.w;
            *(bf16x8*)&As[row][SWB(row, kb) * 8] = p;
        }
        for (int o = t; o < 256 * 8; o += 512) {
            const int row = o >> 3, kb = o & 7;
            *(uint4*)&Bs[row][SWB(row, kb) * 8] =
                *(const uint4*)(w1T + (size_t)(nb * 256 + row) * 256 + kc * 64 + kb * 8);
        }
        __syncthreads();
        #pragma unroll
        for (int kk = 0; kk < 2; ++kk) {
            bf16x8 af[4], bfr[4];
            #pragma unroll
            for (int rt = 0; rt < 4; ++rt) {
                const int ar = wm * 64 + rt * 16 + l15;
                af[rt] = *(const bf16x8*)&As[ar][((kk * 4 + lg) ^ (ar & 7)) * 8];
            }
            #pragma unroll
            for (int ct = 0; ct < 4; ++ct) {
                const int br = wn * 64 + ct * 16 + l15;
                bfr[ct] = *(const bf16x8*)&Bs[br][((kk * 4 + lg) ^ (br & 7)) * 8];
            }
            #pragma unroll
            for (int rt = 0; rt < 4; ++rt)
                #pragma unroll
                for (int ct = 0; ct < 4; ++ct)
                    acc[rt][ct] = MFMA16(af[rt], bfr[ct], acc[rt][ct]);
        }
    }

    #pragma unroll
    for (int ct = 0; ct < 4; ++ct) {
        const int col = nb * 256 + wn * 64 + ct * 16 + l15;
        const float b1 = fc1_b[col];
        #pragma unroll
        for (int rt = 0; rt < 4; ++rt) {
            #pragma unroll
            for (int q = 0; q < 4; ++q) {
                const int rowl = mb * 128 + wm * 64 + rt * 16 + lg * 4 + q;
                hmid[(size_t)rowl * 1024 + col] = (__bf16)gelu_tanh(acc[rt][ct][q] + b1);
            }
        }
    }
}

// ---------------------------------------------------------------------------
// k3b: fc2 + residual + LN2 -> out (one token half). grid 576, block 512
// ---------------------------------------------------------------------------
__global__ __launch_bounds__(512) void k3b_fc2(
    const __bf16* __restrict__ hmid, const __bf16* __restrict__ w2T,
    const float* __restrict__ fc2_b, const float* __restrict__ x1,
    const float* __restrict__ n2w, const float* __restrict__ n2b,
    float* __restrict__ out, int row0)
{
    __shared__ __attribute__((aligned(16))) __bf16 As[128][64];
    __shared__ __attribute__((aligned(16))) __bf16 Bs[256][64];
    __shared__ float ps[128][4], ps2[128][4];
    const int t = threadIdx.x;
    const int wid = t >> 6, lane = t & 63;
    const int l15 = lane & 15, lg = lane >> 4;
    const int mb = blockIdx.x;
    const int wm = wid >> 2, wn = wid & 3;

    const f32x4 fzero = {0.f, 0.f, 0.f, 0.f};
    f32x4 acc[4][4];
    #pragma unroll
    for (int i = 0; i < 4; ++i)
        #pragma unroll
        for (int j = 0; j < 4; ++j) acc[i][j] = fzero;

    for (int kc = 0; kc < 16; ++kc) {
        __syncthreads();
        for (int o = t; o < 128 * 8; o += 512) {
            const int row = o >> 3, kb = o & 7;
            *(uint4*)&As[row][SWB(row, kb) * 8] =
                *(const uint4*)(hmid + (size_t)(mb * 128 + row) * 1024 + kc * 64 + kb * 8);
        }
        for (int o = t; o < 256 * 8; o += 512) {
            const int row = o >> 3, kb = o & 7;
            *(uint4*)&Bs[row][SWB(row, kb) * 8] =
                *(const uint4*)(w2T + (size_t)row * 1024 + kc * 64 + kb * 8);
        }
        __syncthreads();
        #pragma unroll
        for (int kk = 0; kk < 2; ++kk) {
            bf16x8 af[4], bfr[4];
            #pragma unroll
            for (int rt = 0; rt < 4; ++rt) {
                const int ar = wm * 64 + rt * 16 + l15;
                af[rt] = *(const bf16x8*)&As[ar][((kk * 4 + lg) ^ (ar & 7)) * 8];
            }
            #pragma unroll
            for (int ct = 0; ct < 4; ++ct) {
                const int br = wn * 64 + ct * 16 + l15;
                bfr[ct] = *(const bf16x8*)&Bs[br][((kk * 4 + lg) ^ (br & 7)) * 8];
            }
            #pragma unroll
            for (int rt = 0; rt < 4; ++rt)
                #pragma unroll
                for (int ct = 0; ct < 4; ++ct)
                    acc[rt][ct] = MFMA16(af[rt], bfr[ct], acc[rt][ct]);
        }
    }

    #pragma unroll
    for (int rt = 0; rt < 4; ++rt) {
        #pragma unroll
        for (int q = 0; q < 4; ++q) {
            const int rowl = wm * 64 + rt * 16 + lg * 4 + q;
            const size_t tok = (size_t)(row0 + mb * 128 + rowl);
            float s = 0.f, s2 = 0.f;
            #pragma unroll
            for (int ct = 0; ct < 4; ++ct) {
                const int col = wn * 64 + ct * 16 + l15;
                const float v = acc[rt][ct][q] + fc2_b[col] + ALPHA * x1[tok * 256 + col];
                acc[rt][ct][q] = v;
                s += v; s2 += v * v;
            }
            s  += __shfl_xor(s, 1, 16);  s += __shfl_xor(s, 2, 16);
            s  += __shfl_xor(s, 4, 16);  s += __shfl_xor(s, 8, 16);
            s2 += __shfl_xor(s2, 1, 16); s2 += __shfl_xor(s2, 2, 16);
            s2 += __shfl_xor(s2, 4, 16); s2 += __shfl_xor(s2, 8, 16);
            if (l15 == 0) { ps[rowl][wn] = s; ps2[rowl][wn] = s2; }
        }
    }
    __syncthreads();
    #pragma unroll
    for (int rt = 0; rt < 4; ++rt) {
        #pragma unroll
        for (int q = 0; q < 4; ++q) {
            const int rowl = wm * 64 + rt * 16 + lg * 4 + q;
            const size_t tok = (size_t)(row0 + mb * 128 + rowl);
            const float S  = ps[rowl][0] + ps[rowl][1] + ps[rowl][2] + ps[rowl][3];
            const float S2 = ps2[rowl][0] + ps2[rowl][1] + ps2[rowl][2] + ps2[rowl][3];
            const float mu = S * (1.0f / 256.0f);
            const float var = S2 * (1.0f / 256.0f) - mu * mu;
            const float rstd = rsqrtf(var + 1e-5f);
            float* op = out + tok * 256;
            #pragma unroll
            for (int ct = 0; ct < 4; ++ct) {
                const int col = wn * 64 + ct * 16 + l15;
                op[col] = (acc[rt][ct][q] - mu) * rstd * n2w[col] + n2b[col];
            }
        }
    }
}

// ---------------------------------------------------------------------------
extern "C" void kernel_launch(void* const* d_in, const int* in_sizes, int n_in,
                              void* d_out, int out_size, void* d_ws, size_t ws_size,
                              hipStream_t stream)
{
    const float* x          = (const float*)d_in[0];
    const float* qkv_w      = (const float*)d_in[1];
    const float* qkv_b      = (const float*)d_in[2];
    const float* bias_table = (const float*)d_in[3];
    const float* proj_w     = (const float*)d_in[4];
    const float* proj_b     = (const float*)d_in[5];
    const float* n1w        = (const float*)d_in[6];
    const float* n1b        = (const float*)d_in[7];
    const float* n2w        = (const float*)d_in[8];
    const float* n2b        = (const float*)d_in[9];
    const float* fc1_w      = (const float*)d_in[10];
    const float* fc1_b      = (const float*)d_in[11];
    const float* fc2_w      = (const float*)d_in[12];
    const float* fc2_b      = (const float*)d_in[13];
    float* out = (float*)d_out;

    // ws layout (bytes), total 303,562,752 (same footprint as proven rounds):
    //   [0,          226492416)  qkv bf16            (dead after k1b)
    //   [0,          150994944)  x1 fp32             (written by k2; overlays dead qkv)
    //   [150994944,  301989888)  hmid bf16, one half (overlays dead qkv tail + attnout)
    //   [226492416,  301989888)  attnout bf16        (dead after k2)
    //   [301989888,  303562752)  weight tables
    char* ws = (char*)d_ws;
    __bf16* qkv     = (__bf16*)ws;
    float*  x1      = (float*)ws;
    __bf16* hmid    = (__bf16*)(ws + 150994944);
    __bf16* attnout = (__bf16*)(ws + 226492416);
    __bf16* qkvT    = (__bf16*)(ws + 301989888);
    __bf16* projT   = (__bf16*)(ws + 302383104);
    __bf16* w1T     = (__bf16*)(ws + 302514176);
    __bf16* w2T     = (__bf16*)(ws + 303038464);

    k0_prep<<<3072, 256, 0, stream>>>(qkv_w, proj_w, fc1_w, fc2_w, qkvT, projT, w1T, w2T);
    k1a_qkv<<<dim3(1152, 3), 512, 0, stream>>>(x, qkvT, qkv_b, qkv);
    k1b_attn<<<4096, 256, 0, stream>>>(qkv, bias_table, attnout);
    k2_proj_ln<<<1152, 512, 0, stream>>>(attnout, projT, proj_b, x, n1w, n1b, x1);
    for (int h = 0; h < 2; ++h) {
        k3a_fc1<<<dim3(576, 4), 512, 0, stream>>>(x1, w1T, fc1_b, hmid, h * 73728);
        k3b_fc2<<<576, 512, 0, stream>>>(hmid, w2T, fc2_b, x1, n2w, n2b, out, h * 73728);
    }
}